// Round 9
// baseline (562.026 us; speedup 1.0000x reference)
//
#include <hip/hip_runtime.h>
#include <hip/hip_fp16.h>

// GCN encoder: 3 layers of  out = Ddst^-1/2 * A * Dsrc^-1/2 * X * W + b
// N=100000, E=1600000, dims 128->128->128->64, all fp32 in/out.
//
// Round 8: feature-slice partitioning (8 x 16-feature slices, slice-major
// [slice][N][16] fp16 intermediates). Gather blocks take slice = blockIdx%8;
// round-robin blockIdx->XCD puts ONE 3.2 MB X-slice per XCD L2 (round-7
// profile: 258 MB L2-miss re-fetch of a 25.6 MB L3-resident array).
// eidx re-read per slice (8x6.4MB, L3) is the cheap price.
//  - cvt/gather/GEMM all converted to slice-major addressing
//  - CSR build: binbuf packed to u32 (src<<9|dstlocal), srcbuf to u16
//  - MFMA 16x16x32 f16 GEMMs, Wt fp16; epilogue stores now coalesced 32B runs

#define DK 128
#define BIN_SHIFT 9
#define BIN_SIZE 512
#define NBINS_MAX 256
#define P3_CHUNK 8192

typedef _Float16 f16x8 __attribute__((ext_vector_type(8)));
typedef _Float16 f16x16 __attribute__((ext_vector_type(16)));
typedef float f32x4 __attribute__((ext_vector_type(4)));

// ---------- p1: coarse bin counts for dst and src (LDS only) ----------
__global__ __launch_bounds__(256) void p1_count(const int* __restrict__ src,
                                                const int* __restrict__ dst,
                                                int* __restrict__ bin_cnt, int E) {
    __shared__ int hd[NBINS_MAX];
    __shared__ int hs[NBINS_MAX];
    const int tid = threadIdx.x;
    hd[tid] = 0;
    hs[tid] = 0;
    __syncthreads();
    const int stride = gridDim.x * 256;
    for (int e = blockIdx.x * 256 + tid; e < E; e += stride) {
        atomicAdd(&hd[dst[e] >> BIN_SHIFT], 1);
        atomicAdd(&hs[src[e] >> BIN_SHIFT], 1);
    }
    __syncthreads();
    int d = hd[tid], s = hs[tid];
    if (d) atomicAdd(&bin_cnt[tid], d);
    if (s) atomicAdd(&bin_cnt[NBINS_MAX + tid], s);
}

// ---------- p2: exclusive scan of two independent 256-bin segments ----------
__global__ __launch_bounds__(256) void p2_scan(const int* __restrict__ bin_cnt,
                                               int* __restrict__ bin_base,
                                               int* __restrict__ bin_cur) {
    __shared__ int wsum[4];
    const int tid = threadIdx.x;
    const int lane = tid & 63, w = tid >> 6;
    for (int seg = 0; seg < 2; ++seg) {
        int v = bin_cnt[seg * NBINS_MAX + tid];
        int sc = v;
#pragma unroll
        for (int off = 1; off < 64; off <<= 1) {
            int t = __shfl_up(sc, off, 64);
            if (lane >= off) sc += t;
        }
        if (lane == 63) wsum[w] = sc;
        __syncthreads();
        int woff = 0;
        for (int k = 0; k < w; ++k) woff += wsum[k];
        int excl = woff + sc - v;
        bin_base[seg * NBINS_MAX + tid] = excl;
        bin_cur[seg * NBINS_MAX + tid] = excl;
        __syncthreads();
    }
}

// ---------- p3: dual binning scatter (packed payloads) ----------
__global__ __launch_bounds__(256) void p3_scatter(const int* __restrict__ src,
                                                  const int* __restrict__ dst,
                                                  int* __restrict__ bin_cur,
                                                  unsigned* __restrict__ binbuf,
                                                  unsigned short* __restrict__ srcbuf,
                                                  int E) {
    __shared__ int cd[NBINS_MAX];
    __shared__ int cs[NBINS_MAX];
    __shared__ int od[NBINS_MAX];
    __shared__ int osf[NBINS_MAX];
    const int tid = threadIdx.x;
    const int c0 = blockIdx.x * P3_CHUNK;
    const int c1 = min(E, c0 + P3_CHUNK);
    cd[tid] = 0;
    cs[tid] = 0;
    __syncthreads();
    for (int i = c0 + tid; i < c1; i += 256) {
        atomicAdd(&cd[dst[i] >> BIN_SHIFT], 1);
        atomicAdd(&cs[src[i] >> BIN_SHIFT], 1);
    }
    __syncthreads();
    int d = cd[tid], s = cs[tid];
    if (d) od[tid] = atomicAdd(&bin_cur[tid], d);
    if (s) osf[tid] = atomicAdd(&bin_cur[NBINS_MAX + tid], s);
    __syncthreads();
    cd[tid] = 0;
    cs[tid] = 0;
    __syncthreads();
    for (int i = c0 + tid; i < c1; i += 256) {
        int sv = src[i], dv = dst[i];
        int bd = dv >> BIN_SHIFT;
        int p = od[bd] + atomicAdd(&cd[bd], 1);
        binbuf[p] = ((unsigned)sv << BIN_SHIFT) | (unsigned)(dv & (BIN_SIZE - 1));
        int bs = sv >> BIN_SHIFT;
        int q = osf[bs] + atomicAdd(&cs[bs], 1);
        srcbuf[q] = (unsigned short)(sv & (BIN_SIZE - 1));
    }
}

// ---------- p4: per dst-bin finalize: rp, ndst, eidx ----------
__global__ __launch_bounds__(256) void p4_finalize(const unsigned* __restrict__ binbuf,
                                                   const int* __restrict__ bin_base,
                                                   const int* __restrict__ bin_cnt,
                                                   int* __restrict__ rp,
                                                   float* __restrict__ ndst,
                                                   int* __restrict__ eidx, int n) {
    __shared__ int hist[BIN_SIZE];
    __shared__ int wsum[4];
    const int tid = threadIdx.x;
    const int b = blockIdx.x;
    const int ebase = bin_base[b];
    const int count = bin_cnt[b];
    hist[tid] = 0;
    hist[tid + 256] = 0;
    __syncthreads();
    const unsigned* ebuf = binbuf + ebase;
    for (int i = tid; i < count; i += 256)
        atomicAdd(&hist[ebuf[i] & (BIN_SIZE - 1)], 1);
    __syncthreads();
    int v0 = hist[2 * tid], v1 = hist[2 * tid + 1];
    int s = v0 + v1;
    const int lane = tid & 63, w = tid >> 6;
    int sc = s;
#pragma unroll
    for (int off = 1; off < 64; off <<= 1) {
        int t = __shfl_up(sc, off, 64);
        if (lane >= off) sc += t;
    }
    if (lane == 63) wsum[w] = sc;
    __syncthreads();
    int woff = 0;
    for (int k = 0; k < w; ++k) woff += wsum[k];
    const int b0 = woff + sc - s;
    const int b1 = b0 + v0;
    const int g0 = (b << BIN_SHIFT) + 2 * tid;
    if (g0 < n) { rp[g0] = ebase + b0; ndst[g0] = rsqrtf(fmaxf((float)v0, 1.0f)); }
    if (g0 + 1 < n) { rp[g0 + 1] = ebase + b1; ndst[g0 + 1] = rsqrtf(fmaxf((float)v1, 1.0f)); }
    if (b == gridDim.x - 1 && tid == 0) rp[n] = ebase + count;
    __syncthreads();
    hist[2 * tid] = b0;
    hist[2 * tid + 1] = b1;
    __syncthreads();
    for (int i = tid; i < count; i += 256) {
        unsigned e = ebuf[i];
        int p = ebase + atomicAdd(&hist[e & (BIN_SIZE - 1)], 1);
        eidx[p] = (int)(e >> BIN_SHIFT);
    }
}

// ---------- p4b: per src-bin histogram -> nsrc ----------
__global__ __launch_bounds__(256) void p4b_nsrc(const unsigned short* __restrict__ srcbuf,
                                                const int* __restrict__ bin_base,
                                                const int* __restrict__ bin_cnt,
                                                float* __restrict__ nsrc, int n) {
    __shared__ int hist[BIN_SIZE];
    const int tid = threadIdx.x;
    const int b = blockIdx.x;
    const int ebase = bin_base[NBINS_MAX + b];
    const int count = bin_cnt[NBINS_MAX + b];
    hist[tid] = 0;
    hist[tid + 256] = 0;
    __syncthreads();
    const unsigned short* ebuf = srcbuf + ebase;
    for (int i = tid; i < count; i += 256)
        atomicAdd(&hist[ebuf[i]], 1);
    __syncthreads();
    int g = (b << BIN_SHIFT) + tid;
    if (g < n) nsrc[g] = rsqrtf(fmaxf((float)hist[tid], 1.0f));
    g += 256;
    if (g < n) nsrc[g] = rsqrtf(fmaxf((float)hist[tid + 256], 1.0f));
}

// ---------- convert + row-scale into slice-major: x16[j][node][16] ----------
// thread = (slice j = blockIdx%8, node); reads 64B full lines, writes 32B coalesced
__global__ __launch_bounds__(256) void cvt_scale_sl(const float* __restrict__ x,
                                                    const float* __restrict__ scale,
                                                    _Float16* __restrict__ o, int n) {
    const int j = blockIdx.x & 7;
    const int node = (blockIdx.x >> 3) * 256 + threadIdx.x;
    if (node >= n) return;
    const float s = scale[node];
    const float4* r = (const float4*)(x + (size_t)node * 128 + j * 16);
    float4 v0 = r[0], v1 = r[1], v2 = r[2], v3 = r[3];
    f16x16 h;
    h[0]  = (_Float16)(v0.x * s); h[1]  = (_Float16)(v0.y * s);
    h[2]  = (_Float16)(v0.z * s); h[3]  = (_Float16)(v0.w * s);
    h[4]  = (_Float16)(v1.x * s); h[5]  = (_Float16)(v1.y * s);
    h[6]  = (_Float16)(v1.z * s); h[7]  = (_Float16)(v1.w * s);
    h[8]  = (_Float16)(v2.x * s); h[9]  = (_Float16)(v2.y * s);
    h[10] = (_Float16)(v2.z * s); h[11] = (_Float16)(v2.w * s);
    h[12] = (_Float16)(v3.x * s); h[13] = (_Float16)(v3.y * s);
    h[14] = (_Float16)(v3.z * s); h[15] = (_Float16)(v3.w * s);
    *(f16x16*)(o + ((size_t)j * n + node) * 16) = h;
}

// ---------- weight convert+transpose (all three in one launch) ----------
__global__ __launch_bounds__(256) void wcvt_all(const float* __restrict__ W0,
                                                const float* __restrict__ W1,
                                                const float* __restrict__ W2,
                                                _Float16* __restrict__ Wt0,
                                                _Float16* __restrict__ Wt1,
                                                _Float16* __restrict__ Wt2) {
    int i = blockIdx.x * 256 + threadIdx.x;
    if (i < 16384) {
        int k = i >> 7, c = i & 127;
        Wt0[(size_t)c * 128 + k] = (_Float16)W0[i];
    } else if (i < 32768) {
        int j = i - 16384;
        int k = j >> 7, c = j & 127;
        Wt1[(size_t)c * 128 + k] = (_Float16)W1[j];
    } else if (i < 40960) {
        int j = i - 32768;
        int k = j >> 6, c = j & 63;
        Wt2[(size_t)c * 128 + k] = (_Float16)W2[j];
    }
}

// ---------- slice-major SpMM gather ----------
// NS = total 16-feature slices (8 for 128-wide, 4 for 64-wide).
// slice j = blockIdx % NS -> XCD-local X working set (round-robin dispatch).
// !FINAL: out16[j][node][16] = fp16( ndst[node] * sum_e x[j][src_e][16] )
//  FINAL: out32[node][NS*16] = ndst[node] * sum + bias
template <int NS, bool FINAL>
__global__ __launch_bounds__(256) void spmm_gather_sl(const _Float16* __restrict__ x,
                                                      const int* __restrict__ eidx,
                                                      const int* __restrict__ rp,
                                                      const float* __restrict__ ndst,
                                                      const float* __restrict__ bias,
                                                      void* __restrict__ outv, int n) {
    const int j = blockIdx.x % NS;
    const int node = (blockIdx.x / NS) * 256 + threadIdx.x;
    if (node >= n) return;
    const _Float16* xs = x + (size_t)j * n * 16;
    const int beg = rp[node];
    const int end = rp[node + 1];
    float a0[8] = {0.f, 0.f, 0.f, 0.f, 0.f, 0.f, 0.f, 0.f};
    float a1[8] = {0.f, 0.f, 0.f, 0.f, 0.f, 0.f, 0.f, 0.f};
#pragma unroll 2
    for (int e = beg; e < end; ++e) {
        int s = eidx[e];
        f16x8 v0 = *(const f16x8*)(xs + (size_t)s * 16);
        f16x8 v1 = *(const f16x8*)(xs + (size_t)s * 16 + 8);
#pragma unroll
        for (int t = 0; t < 8; ++t) { a0[t] += (float)v0[t]; a1[t] += (float)v1[t]; }
    }
    const float sd = ndst[node];
    if (FINAL) {
        float* o = (float*)outv + (size_t)node * (NS * 16) + j * 16;
        const float4* bj = (const float4*)(bias + j * 16);
        float4 b0 = bj[0], b1 = bj[1], b2 = bj[2], b3 = bj[3];
        ((float4*)o)[0] = make_float4(a0[0] * sd + b0.x, a0[1] * sd + b0.y,
                                      a0[2] * sd + b0.z, a0[3] * sd + b0.w);
        ((float4*)o)[1] = make_float4(a0[4] * sd + b1.x, a0[5] * sd + b1.y,
                                      a0[6] * sd + b1.z, a0[7] * sd + b1.w);
        ((float4*)o)[2] = make_float4(a1[0] * sd + b2.x, a1[1] * sd + b2.y,
                                      a1[2] * sd + b2.z, a1[3] * sd + b2.w);
        ((float4*)o)[3] = make_float4(a1[4] * sd + b3.x, a1[5] * sd + b3.y,
                                      a1[6] * sd + b3.z, a1[7] * sd + b3.w);
    } else {
        f16x16 h;
#pragma unroll
        for (int t = 0; t < 8; ++t) {
            h[t] = (_Float16)(a0[t] * sd);
            h[t + 8] = (_Float16)(a1[t] * sd);
        }
        *(f16x16*)((_Float16*)outv + ((size_t)j * n + node) * 16) = h;
    }
}

// ---------- MFMA GEMM, slice-major A and Y ----------
// A[8][n][16] fp16 (K=128); Wt[C][128] fp16; Y[C/16][n][16] fp16.
// Y = fp16( oscale? * (A @ W + bias?) ). Requires n % 16 == 0.
template <int C, bool OSCALE, bool BIAS>
__global__ __launch_bounds__(256) void mfma_gemm(const _Float16* __restrict__ A,
                                                 const _Float16* __restrict__ Wt,
                                                 const float* __restrict__ bias,
                                                 const float* __restrict__ oscale,
                                                 _Float16* __restrict__ Y, int n) {
    constexpr int K = DK;   // 128
    const int wid = threadIdx.x >> 6;
    const int lane = threadIdx.x & 63;
    const int row0 = (blockIdx.x * 4 + wid) * 16;
    if (row0 >= n) return;
    const int lr = lane & 15;
    const int hi = lane >> 4;          // 0..3
    const int lk = hi * 8;             // k-offset within each 32-chunk
    const int row = row0 + lr;

    // A fragments: a[s] covers k in [s*32+lk, s*32+lk+8) -> slice 2s+(hi>>1), off (hi&1)*8
    f16x8 a[4];
#pragma unroll
    for (int s = 0; s < 4; ++s) {
        const int sl = 2 * s + (hi >> 1);
        a[s] = *(const f16x8*)(A + ((size_t)sl * n + row) * 16 + (hi & 1) * 8);
    }

    const int rbase = row0 + hi * 4;
    float os[4];
    if (OSCALE) {
#pragma unroll
        for (int j = 0; j < 4; ++j) os[j] = oscale[rbase + j];
    }

#pragma unroll
    for (int ct = 0; ct < C / 16; ++ct) {
        const int col = ct * 16 + lr;
        const _Float16* wrow = Wt + (size_t)col * K + lk;
        f32x4 acc = {0.f, 0.f, 0.f, 0.f};
#pragma unroll
        for (int s = 0; s < 4; ++s) {
            f16x8 b = *(const f16x8*)(wrow + s * 32);
            acc = __builtin_amdgcn_mfma_f32_16x16x32_f16(a[s], b, acc, 0, 0, 0);
        }
        const float bv = BIAS ? bias[col] : 0.f;
#pragma unroll
        for (int j = 0; j < 4; ++j) {
            float o = acc[j] + bv;
            if (OSCALE) o *= os[j];
            Y[((size_t)ct * n + (rbase + j)) * 16 + lr] = (_Float16)o;
        }
    }
}

static inline int cdiv(long long a, long long b) { return (int)((a + b - 1) / b); }

extern "C" void kernel_launch(void* const* d_in, const int* in_sizes, int n_in,
                              void* d_out, int out_size, void* d_ws, size_t ws_size,
                              hipStream_t stream) {
    const float* feat = (const float*)d_in[0];
    const float* W0   = (const float*)d_in[1];
    const float* b0   = (const float*)d_in[2];
    const float* W1   = (const float*)d_in[3];
    const float* b1   = (const float*)d_in[4];
    const float* W2   = (const float*)d_in[5];
    const float* b2   = (const float*)d_in[6];
    const int*   src  = (const int*)d_in[7];
    const int*   dst  = (const int*)d_in[8];

    const int N = in_sizes[0] / DK;
    const int E = in_sizes[7];

    // ws (4B units): nsrc[N] ndst[N] rp[N+1] bin_cnt[512] bin_base[512]
    //                bin_cur[512] eidx[E] | xbuf(fp16 [8][N][16]) abuf(same)
    //                Wt0/Wt1/Wt2 (fp16)
    // aliases: binbuf (u32, E)  -> xbuf region (dead before cvt_scale)
    //          srcbuf (u16, E)  -> abuf region (dead before gather0 writes)
    float* ws       = (float*)d_ws;
    float* nsrc     = ws;
    float* ndst     = ws + N;
    int*   rp       = (int*)(ws + 2 * (size_t)N);
    int*   bin_cnt  = rp + (N + 1);
    int*   bin_base = bin_cnt + 2 * NBINS_MAX;
    int*   bin_cur  = bin_base + 2 * NBINS_MAX;
    int*   eidx     = bin_cur + 2 * NBINS_MAX;
    size_t aoff     = (size_t)(3 * (size_t)N + 1 + 6 * NBINS_MAX + E + 15) & ~(size_t)15;
    _Float16* xbuf  = (_Float16*)(ws + aoff);                    // [8][N][16] fp16
    _Float16* abuf  = (_Float16*)(ws + aoff + (size_t)N * 64);   // [8][N][16] fp16
    _Float16* Wt0   = (_Float16*)(ws + aoff + (size_t)N * 128);
    _Float16* Wt1   = Wt0 + 128 * 128;
    _Float16* Wt2   = Wt1 + 128 * 128;
    unsigned* binbuf        = (unsigned*)xbuf;
    unsigned short* srcbuf  = (unsigned short*)abuf;

    const int NBINS_USED = cdiv(N, BIN_SIZE);

    // ---- CSR + norms build ----
    hipMemsetAsync(bin_cnt, 0, 2 * NBINS_MAX * sizeof(int), stream);
    p1_count<<<256, 256, 0, stream>>>(src, dst, bin_cnt, E);
    p2_scan<<<1, 256, 0, stream>>>(bin_cnt, bin_base, bin_cur);
    p3_scatter<<<cdiv(E, P3_CHUNK), 256, 0, stream>>>(src, dst, bin_cur, binbuf, srcbuf, E);
    p4_finalize<<<NBINS_USED, 256, 0, stream>>>(binbuf, bin_base, bin_cnt, rp, ndst, eidx, N);
    p4b_nsrc<<<NBINS_USED, 256, 0, stream>>>(srcbuf, bin_base, bin_cnt, nsrc, N);

    // ---- weight convert+transpose ----
    wcvt_all<<<160, 256, 0, stream>>>(W0, W1, W2, Wt0, Wt1, Wt2);

    const int nchunks = cdiv(N, 256);
    const int gat128 = nchunks * 8;   // 8 slices
    const int gat64  = nchunks * 4;   // 4 slices
    const int gemm_blocks = cdiv(N, 64);

    // ---- layer 0 ----
    cvt_scale_sl<<<nchunks * 8, 256, 0, stream>>>(feat, nsrc, xbuf, N);
    spmm_gather_sl<8, false><<<gat128, 256, 0, stream>>>(xbuf, eidx, rp, ndst, nullptr, abuf, N);
    mfma_gemm<128, true, true><<<gemm_blocks, 256, 0, stream>>>(abuf, Wt0, b0, nsrc, xbuf, N);

    // ---- layer 1 ----
    spmm_gather_sl<8, false><<<gat128, 256, 0, stream>>>(xbuf, eidx, rp, ndst, nullptr, abuf, N);
    mfma_gemm<128, false, true><<<gemm_blocks, 256, 0, stream>>>(abuf, Wt1, b1, nullptr, xbuf, N);

    // ---- layer 2 ----
    mfma_gemm<64, true, false><<<gemm_blocks, 256, 0, stream>>>(xbuf, Wt2, nullptr, nsrc, abuf, N);
    spmm_gather_sl<4, true><<<gat64, 256, 0, stream>>>(abuf, eidx, rp, ndst, b2, d_out, N);
}